// Round 10
// baseline (516.056 us; speedup 1.0000x reference)
//
#include <hip/hip_runtime.h>
#include <math.h>

#define NLV 16
#define LOG2_T 19
#define T_SIZE (1u << LOG2_T)
#define T_MASK (T_SIZE - 1u)
#define P2 2654435761u
#define P3 805459861u
#define NBUCK 32768   // 32^3 Morton buckets

typedef float vf2 __attribute__((ext_vector_type(2)));
typedef float vf4 __attribute__((ext_vector_type(4)));

struct Scales { float s[NLV]; };
// Linear-repack config for levels 0..7 (tables that fit in borrowed enc space).
struct RpCfg {
    unsigned cellOff[9];          // prefix sums of D^3, cellOff[8] = total cells
    unsigned D[8];                // linear grid dim per level
    unsigned long long rpOff[8];  // float offset of level l's repacked table
};

// ---------- Morton key (5 bits/axis) ----------
__device__ __forceinline__ unsigned mpart(unsigned v) {
    v = (v | (v << 8)) & 0x100Fu;
    v = (v | (v << 4)) & 0x10C3u;
    v = (v | (v << 2)) & 0x1249u;
    return v;
}
__device__ __forceinline__ unsigned mkey(float px, float py, float pz) {
    unsigned cx = (unsigned)(px * 32.f); cx = cx > 31u ? 31u : cx;
    unsigned cy = (unsigned)(py * 32.f); cy = cy > 31u ? 31u : cy;
    unsigned cz = (unsigned)(pz * 32.f); cz = cz > 31u ? 31u : cz;
    return mpart(cx) | (mpart(cy) << 1) | (mpart(cz) << 2);
}

// ---------- sort kernels (1 pt/thread: latency-bound, maximize wave count) ----------
__global__ __launch_bounds__(256) void zero_hist_kernel(unsigned* hist) {
    int i = blockIdx.x * 256 + threadIdx.x;
    if (i < NBUCK) hist[i] = 0u;
}

__global__ __launch_bounds__(256) void hist_kernel(
    const float* __restrict__ x, unsigned* __restrict__ hist, int N)
{
    const int i = blockIdx.x * 256 + threadIdx.x;
    if (i >= N) return;
    const float px = x[3 * (size_t)i + 0];
    const float py = x[3 * (size_t)i + 1];
    const float pz = x[3 * (size_t)i + 2];
    atomicAdd(&hist[mkey(px, py, pz)], 1u);
}

__global__ __launch_bounds__(1024) void scan_kernel(unsigned* hist) {
    __shared__ unsigned tot[1024];
    const int t = threadIdx.x;
    const unsigned base = (unsigned)t * 32u;
    unsigned loc[32];
    unsigned s = 0;
    #pragma unroll
    for (int k = 0; k < 32; ++k) { loc[k] = s; s += hist[base + k]; }
    tot[t] = s;
    __syncthreads();
    for (int off = 1; off < 1024; off <<= 1) {
        unsigned u = (t >= off) ? tot[t - off] : 0u;
        __syncthreads();
        tot[t] += u;
        __syncthreads();
    }
    const unsigned excl = tot[t] - s;
    #pragma unroll
    for (int k = 0; k < 32; ++k) hist[base + k] = excl + loc[k];
}

// One 16B record per point: {px,py,pz, bitcast(idx)} -> single line touch.
__global__ __launch_bounds__(256) void scatter_kernel(
    const float* __restrict__ x, unsigned* __restrict__ cursor,
    vf4* __restrict__ xs, int N)
{
    const int i = blockIdx.x * 256 + threadIdx.x;
    if (i >= N) return;
    const float px = x[3 * (size_t)i + 0];
    const float py = x[3 * (size_t)i + 1];
    const float pz = x[3 * (size_t)i + 2];
    const unsigned key = mkey(px, py, pz);
    const unsigned pos = atomicAdd(&cursor[key], 1u);
    vf4 v; v[0] = px; v[1] = py; v[2] = pz; v[3] = __int_as_float(i);
    xs[pos] = v;
}

// ---------- repack: hash table -> linear (iz*D+iy)*D+ix layout, exact copies ----------
__global__ __launch_bounds__(256) void repack_all_kernel(
    const float* __restrict__ table, float* __restrict__ rp, RpCfg cfg)
{
    const unsigned tid = blockIdx.x * 256 + threadIdx.x;
    if (tid >= cfg.cellOff[8]) return;
    unsigned l = 0;
    #pragma unroll
    for (int k = 1; k < 8; ++k) if (tid >= cfg.cellOff[k]) l = k;
    const unsigned c = tid - cfg.cellOff[l];
    const unsigned D = cfg.D[l];
    const unsigned ix = c % D;
    const unsigned t2 = c / D;
    const unsigned iy = t2 % D;
    const unsigned iz = t2 / D;
    const unsigned h = (ix ^ (iy * P2) ^ (iz * P3)) & T_MASK;
    const float* tl = table + (size_t)l * T_SIZE * 2u;
    *(vf2*)(rp + cfg.rpOff[l] + 2u * (size_t)c) = *(const vf2*)(tl + 2u * (size_t)h);
}

// ---------- encode (linear repacked path): sorted-adjacent lanes read adjacent
// addresses -> the TA's per-instruction same-line dedup collapses 64 lane
// addresses to few distinct lines. Loads/weights/order identical to hash path
// -> bit-identical output.
__device__ __forceinline__ void enc_level_lin(
    float px, float py, float pz, float s, const float* __restrict__ rp, unsigned D,
    float& f0, float& f1)
{
    const float fx = px * s, fy = py * s, fz = pz * s;
    const float bx = floorf(fx), by = floorf(fy), bz = floorf(fz);
    const float rx = fx - bx, ry = fy - by, rz = fz - bz;
    const unsigned ix0 = (unsigned)bx, iy0 = (unsigned)by, iz0 = (unsigned)bz;
    const float wx0 = 1.f - rx, wy0 = 1.f - ry, wz0 = 1.f - rz;
    const unsigned D2 = D * D;
    const unsigned base = (iz0 * D + iy0) * D + ix0;
    f0 = 0.f; f1 = 0.f;
    #pragma unroll
    for (int c = 0; c < 8; ++c) {
        const unsigned idx = base + ((c & 4) ? 1u : 0u) + ((c & 2) ? D : 0u) + ((c & 1) ? D2 : 0u);
        const vf2 f = *(const vf2*)(rp + 2u * (size_t)idx);
        const float w = ((c & 4) ? rx : wx0) * ((c & 2) ? ry : wy0) * ((c & 1) ? rz : wz0);
        f0 += w * f[0];
        f1 += w * f[1];
    }
}

__global__ __launch_bounds__(256) void encode_coarse_lin_kernel(
    const vf4* __restrict__ xs, const float* __restrict__ rp,
    float* __restrict__ enc, int N, Scales sc, RpCfg cfg)
{
    int i = blockIdx.x * 256 + threadIdx.x;
    if (i >= N) return;
    const vf4 p = xs[i];
    #pragma unroll
    for (int l = 0; l < 5; ++l) {
        float f0, f1;
        enc_level_lin(p[0], p[1], p[2], sc.s[l], rp + cfg.rpOff[l], cfg.D[l], f0, f1);
        vf2 v; v[0] = f0; v[1] = f1;
        *(vf2*)(enc + ((size_t)l * N + i) * 2u) = v;
    }
}

template<int LVL>
__global__ __launch_bounds__(256) void encode_fine_lin_kernel(
    const vf4* __restrict__ xs, const float* __restrict__ rpl, unsigned D, float s,
    float* __restrict__ encl, int N)
{
    const int i0 = blockIdx.x * 1024 + threadIdx.x;
    #pragma unroll
    for (int k = 0; k < 4; ++k) {
        const int i = i0 + k * 256;
        if (i < N) {
            const vf4 p = xs[i];
            float f0, f1;
            enc_level_lin(p[0], p[1], p[2], s, rpl, D, f0, f1);
            vf2 v; v[0] = f0; v[1] = f1;
            *(vf2*)(encl + (size_t)i * 2u) = v;
        }
    }
}

// ---------- encode (hash path, levels 8..15 + fallbacks) ----------
// PRIMES[0]==1: paired x-corners share one 16B entry pair when ix even.
__device__ __forceinline__ void enc_level(
    float px, float py, float pz, float s, const float* __restrict__ tl,
    float& f0, float& f1)
{
    const float fx = px * s, fy = py * s, fz = pz * s;
    const float bx = floorf(fx), by = floorf(fy), bz = floorf(fz);
    const float rx = fx - bx, ry = fy - by, rz = fz - bz;
    const unsigned ix0 = (unsigned)bx, iy0 = (unsigned)by, iz0 = (unsigned)bz;
    const unsigned hy0 = iy0 * P2, hy1 = (iy0 + 1u) * P2;
    const unsigned hz0 = iz0 * P3, hz1 = (iz0 + 1u) * P3;
    const float wx0 = 1.f - rx, wy0 = 1.f - ry, wz0 = 1.f - rz;
    f0 = 0.f; f1 = 0.f;
    if (!(ix0 & 1u)) {
        float c0[8], c1[8];
        #pragma unroll
        for (int yz = 0; yz < 4; ++yz) {
            const unsigned r = ((yz & 2) ? hy1 : hy0) ^ ((yz & 1) ? hz1 : hz0);
            const unsigned h0 = (ix0 ^ r) & T_MASK;
            const vf4 q = *(const vf4*)(tl + 2u * (size_t)(h0 & ~1u));
            const bool odd = (h0 & 1u) != 0u;
            c0[yz]     = odd ? q[2] : q[0];
            c1[yz]     = odd ? q[3] : q[1];
            c0[4 + yz] = odd ? q[0] : q[2];
            c1[4 + yz] = odd ? q[1] : q[3];
        }
        #pragma unroll
        for (int c = 0; c < 8; ++c) {
            const float w = ((c & 4) ? rx : wx0) * ((c & 2) ? ry : wy0) * ((c & 1) ? rz : wz0);
            f0 += w * c0[(c >> 2) * 4 + (c & 3)];
            f1 += w * c1[(c >> 2) * 4 + (c & 3)];
        }
    } else {
        const unsigned hx0 = ix0, hx1 = ix0 + 1u;
        #pragma unroll
        for (int c = 0; c < 8; ++c) {
            unsigned h = ((c & 4) ? hx1 : hx0) ^ ((c & 2) ? hy1 : hy0) ^ ((c & 1) ? hz1 : hz0);
            h &= T_MASK;
            const vf2 f = *(const vf2*)(tl + 2u * (size_t)h);
            const float w = ((c & 4) ? rx : wx0) * ((c & 2) ? ry : wy0) * ((c & 1) ? rz : wz0);
            f0 += w * f[0];
            f1 += w * f[1];
        }
    }
}

__global__ __launch_bounds__(256) void encode_coarse_kernel(
    const vf4* __restrict__ xs, const float* __restrict__ table,
    float* __restrict__ enc, int N, Scales sc)
{
    int i = blockIdx.x * 256 + threadIdx.x;
    if (i >= N) return;
    const vf4 p = xs[i];
    #pragma unroll
    for (int l = 0; l < 5; ++l) {
        float f0, f1;
        enc_level(p[0], p[1], p[2], sc.s[l], table + (size_t)l * T_SIZE * 2u, f0, f1);
        vf2 v; v[0] = f0; v[1] = f1;
        *(vf2*)(enc + ((size_t)l * N + i) * 2u) = v;
    }
}

template<int LVL>
__global__ __launch_bounds__(256) void encode_fine_kernel(
    const vf4* __restrict__ xs, const float* __restrict__ tl, float s,
    float* __restrict__ encl, int N)
{
    const int i0 = blockIdx.x * 1024 + threadIdx.x;
    #pragma unroll
    for (int k = 0; k < 4; ++k) {
        const int i = i0 + k * 256;
        if (i < N) {
            const vf4 p = xs[i];
            float f0, f1;
            enc_level(p[0], p[1], p[2], s, tl, f0, f1);
            vf2 v; v[0] = f0; v[1] = f1;
            *(vf2*)(encl + (size_t)i * 2u) = v;
        }
    }
}

// ---------- MLP: 512 pts/block in two 256-pt halves (17 KB LDS -> 8 blocks/CU),
// float2-pair accumulation, LDS-staged cooperative NT store ----------
__global__ __launch_bounds__(256) void mlp_kernel(
    const float* __restrict__ enc, const vf4* __restrict__ xs,
    const float* __restrict__ W0, const float* __restrict__ b0,
    const float* __restrict__ W1, const float* __restrict__ b1,
    const float* __restrict__ W2, const float* __restrict__ b2,
    float* __restrict__ out, int N)
{
    __shared__ float st[256 * 17];   // 17408 B
    const int base = blockIdx.x * 512;
    const int t = threadIdx.x;
    const float* xsf = (const float*)xs;

    #pragma unroll
    for (int q = 0; q < 2; ++q) {
        if (q) __syncthreads();              // st reuse hazard (uniform branch)
        const int i = base + q * 256 + t;
        if (i < N) {
            vf2 e2[16];
            #pragma unroll
            for (int l = 0; l < NLV; ++l)
                e2[l] = *(const vf2*)(enc + ((size_t)l * N + i) * 2u);

            vf2 a0v[8];
            #pragma unroll
            for (int j = 0; j < 16; ++j) {
                vf2 acc = {0.f, 0.f};
                #pragma unroll
                for (int l = 0; l < 16; ++l)
                    acc += e2[l] * *(const vf2*)(W0 + j * 32 + 2 * l);
                a0v[j >> 1][j & 1] = fmaxf(b0[j] + acc[0] + acc[1], 0.f);
            }
            vf2 a1v[8];
            #pragma unroll
            for (int j = 0; j < 16; ++j) {
                vf2 acc = {0.f, 0.f};
                #pragma unroll
                for (int k = 0; k < 8; ++k)
                    acc += a0v[k] * *(const vf2*)(W1 + j * 16 + 2 * k);
                a1v[j >> 1][j & 1] = fmaxf(b1[j] + acc[0] + acc[1], 0.f);
            }
            #pragma unroll
            for (int j = 0; j < 16; ++j) {
                vf2 acc = {0.f, 0.f};
                #pragma unroll
                for (int k = 0; k < 8; ++k)
                    acc += a1v[k] * *(const vf2*)(W2 + j * 16 + 2 * k);
                st[t * 17 + j] = b2[j] + acc[0] + acc[1];
            }
        }
        __syncthreads();

        const int c = t & 3;
        #pragma unroll
        for (int w = 0; w < 4; ++w) {
            const int p = (t >> 2) + w * 64;          // local row 0..255
            const int gi = base + q * 256 + p;
            if (gi < N) {
                const int dst = __float_as_int(xsf[4 * (size_t)gi + 3]);
                const vf4 v = *(const vf4*)&st[p * 17 + 4 * c];
                __builtin_nontemporal_store(v, (vf4*)(out + 16 * (size_t)dst + 4 * c));
            }
        }
    }
}

// ---------- fallback paths ----------
__global__ __launch_bounds__(256) void encode_coarse_unsorted_kernel(
    const float* __restrict__ x, const float* __restrict__ table,
    float* __restrict__ enc, int N, Scales sc)
{
    int i = blockIdx.x * 256 + threadIdx.x;
    if (i >= N) return;
    const float px = x[3 * (size_t)i + 0];
    const float py = x[3 * (size_t)i + 1];
    const float pz = x[3 * (size_t)i + 2];
    #pragma unroll
    for (int l = 0; l < 5; ++l) {
        float f0, f1;
        enc_level(px, py, pz, sc.s[l], table + (size_t)l * T_SIZE * 2u, f0, f1);
        vf2 v; v[0] = f0; v[1] = f1;
        *(vf2*)(enc + ((size_t)l * N + i) * 2u) = v;
    }
}
__global__ __launch_bounds__(256) void encode_one_unsorted_kernel(
    const float* __restrict__ x, const float* __restrict__ tl, float s,
    float* __restrict__ encl, int N)
{
    int i = blockIdx.x * 256 + threadIdx.x;
    if (i >= N) return;
    const float px = x[3 * (size_t)i + 0];
    const float py = x[3 * (size_t)i + 1];
    const float pz = x[3 * (size_t)i + 2];
    float f0, f1;
    enc_level(px, py, pz, s, tl, f0, f1);
    vf2 v; v[0] = f0; v[1] = f1;
    *(vf2*)(encl + (size_t)i * 2u) = v;
}
__global__ __launch_bounds__(256) void mlp_noperm_kernel(
    const float* __restrict__ enc,
    const float* __restrict__ W0, const float* __restrict__ b0,
    const float* __restrict__ W1, const float* __restrict__ b1,
    const float* __restrict__ W2, const float* __restrict__ b2,
    float* __restrict__ out, int N)
{
    int i = blockIdx.x * 256 + threadIdx.x;
    if (i >= N) return;
    float e[32];
    #pragma unroll
    for (int l = 0; l < NLV; ++l) {
        vf2 v = *(const vf2*)(enc + ((size_t)l * N + i) * 2u);
        e[2 * l + 0] = v[0];
        e[2 * l + 1] = v[1];
    }
    float a0[16];
    #pragma unroll
    for (int j = 0; j < 16; ++j) {
        float s = b0[j];
        #pragma unroll
        for (int k = 0; k < 32; ++k) s += e[k] * W0[j * 32 + k];
        a0[j] = fmaxf(s, 0.f);
    }
    float a1[16];
    #pragma unroll
    for (int j = 0; j < 16; ++j) {
        float s = b1[j];
        #pragma unroll
        for (int k = 0; k < 16; ++k) s += a0[k] * W1[j * 16 + k];
        a1[j] = fmaxf(s, 0.f);
    }
    #pragma unroll
    for (int j = 0; j < 16; ++j) {
        float s = b2[j];
        #pragma unroll
        for (int k = 0; k < 16; ++k) s += a1[k] * W2[j * 16 + k];
        out[16 * (size_t)i + j] = s;
    }
}
__global__ __launch_bounds__(256) void tcnn_fused_kernel(
    const float* __restrict__ x, const float* __restrict__ table,
    const float* __restrict__ W0, const float* __restrict__ b0,
    const float* __restrict__ W1, const float* __restrict__ b1,
    const float* __restrict__ W2, const float* __restrict__ b2,
    float* __restrict__ out, int N, Scales sc)
{
    int i = blockIdx.x * blockDim.x + threadIdx.x;
    if (i >= N) return;
    const float px = x[3 * (size_t)i + 0];
    const float py = x[3 * (size_t)i + 1];
    const float pz = x[3 * (size_t)i + 2];
    float e[32];
    #pragma unroll
    for (int l = 0; l < NLV; ++l) {
        float f0, f1;
        enc_level(px, py, pz, sc.s[l], table + (size_t)l * T_SIZE * 2u, f0, f1);
        e[2 * l] = f0; e[2 * l + 1] = f1;
    }
    float a0[16];
    #pragma unroll
    for (int j = 0; j < 16; ++j) {
        float s = b0[j];
        #pragma unroll
        for (int k = 0; k < 32; ++k) s += e[k] * W0[j * 32 + k];
        a0[j] = fmaxf(s, 0.f);
    }
    float a1[16];
    #pragma unroll
    for (int j = 0; j < 16; ++j) {
        float s = b1[j];
        #pragma unroll
        for (int k = 0; k < 16; ++k) s += a0[k] * W1[j * 16 + k];
        a1[j] = fmaxf(s, 0.f);
    }
    #pragma unroll
    for (int j = 0; j < 16; ++j) {
        float s = b2[j];
        #pragma unroll
        for (int k = 0; k < 16; ++k) s += a1[k] * W2[j * 16 + k];
        out[16 * (size_t)i + j] = s;
    }
}

extern "C" void kernel_launch(void* const* d_in, const int* in_sizes, int n_in,
                              void* d_out, int out_size, void* d_ws, size_t ws_size,
                              hipStream_t stream) {
    const float* x     = (const float*)d_in[0];
    const float* table = (const float*)d_in[1];
    const float* W0    = (const float*)d_in[2];
    const float* b0    = (const float*)d_in[3];
    const float* W1    = (const float*)d_in[4];
    const float* b1    = (const float*)d_in[5];
    const float* W2    = (const float*)d_in[6];
    const float* b2    = (const float*)d_in[7];
    float* out = (float*)d_out;

    const int N = in_sizes[0] / 3;

    Scales sc;
    const double pls = exp2(log2(2048.0 / 16.0) / 15.0);  // matches numpy double math
    for (int l = 0; l < NLV; ++l) sc.s[l] = (float)(16.0 * pow(pls, (double)l));

    // Linear-repack config for levels 0..7.
    RpCfg cfg;
    {
        unsigned long long off = 0;
        unsigned cells = 0;
        for (int l = 0; l < 8; ++l) {
            int D = (int)floor((double)sc.s[l]) + 2;
            if (D & 1) ++D;                       // even pad
            cfg.D[l] = (unsigned)D;
            cfg.cellOff[l] = cells;
            cfg.rpOff[l] = off;
            const unsigned c = (unsigned)D * (unsigned)D * (unsigned)D;
            cells += c;
            off += 2ull * c;
        }
        cfg.cellOff[8] = cells;
    }
    const unsigned long long rpFloats = cfg.rpOff[7] +
        2ull * cfg.D[7] * cfg.D[7] * cfg.D[7];

    const int block = 256;
    const int grid = (N + block - 1) / block;

    const size_t encB  = (size_t)N * 2u * NLV * sizeof(float);   // 128 MiB
    const size_t xsB   = (size_t)N * sizeof(float) * 4u;         //  16 MiB
    const size_t histB = (size_t)NBUCK * sizeof(unsigned);
    // repacked tables borrow enc regions 9..15 (written only by fine 9..15 later)
    const bool rpFits = rpFloats <= (unsigned long long)(NLV - 9) * (size_t)N * 2u;

    if (ws_size >= encB + xsB + histB) {
        float*    enc  = (float*)d_ws;
        vf4*      xs   = (vf4*)((char*)d_ws + encB);
        unsigned* hist = (unsigned*)((char*)d_ws + encB + xsB);

        zero_hist_kernel<<<(NBUCK + 255) / 256, block, 0, stream>>>(hist);
        hist_kernel<<<grid, block, 0, stream>>>(x, hist, N);
        scan_kernel<<<1, 1024, 0, stream>>>(hist);
        scatter_kernel<<<grid, block, 0, stream>>>(x, hist, xs, N);

        const int gridQ = (N + 1023) / 1024;   // 4 pts/thread fine kernels

        if (rpFits) {
            float* rp = enc + (size_t)9 * N * 2u;
            const int gridR = (int)((cfg.cellOff[8] + 255u) / 256u);
            repack_all_kernel<<<gridR, block, 0, stream>>>(table, rp, cfg);

            encode_coarse_lin_kernel<<<grid, block, 0, stream>>>(xs, rp, enc, N, sc, cfg);

            #define LAUNCH_FINE_LIN(L) \
                encode_fine_lin_kernel<L><<<gridQ, block, 0, stream>>>( \
                    xs, rp + cfg.rpOff[(L)], cfg.D[(L)], sc.s[(L)], \
                    enc + (size_t)(L) * (size_t)N * 2u, N)
            LAUNCH_FINE_LIN(5); LAUNCH_FINE_LIN(6); LAUNCH_FINE_LIN(7);
            #undef LAUNCH_FINE_LIN
        } else {
            encode_coarse_kernel<<<grid, block, 0, stream>>>(xs, table, enc, N, sc);
            #define LAUNCH_FINE_H(L) \
                encode_fine_kernel<L><<<gridQ, block, 0, stream>>>( \
                    xs, table + (size_t)(L) * T_SIZE * 2u, sc.s[(L)], \
                    enc + (size_t)(L) * (size_t)N * 2u, N)
            LAUNCH_FINE_H(5); LAUNCH_FINE_H(6); LAUNCH_FINE_H(7);
            #undef LAUNCH_FINE_H
        }

        // hash levels 8..15 (these overwrite the borrowed repack area in enc 9..15)
        #define LAUNCH_FINE(L) \
            encode_fine_kernel<L><<<gridQ, block, 0, stream>>>( \
                xs, table + (size_t)(L) * T_SIZE * 2u, sc.s[(L)], \
                enc + (size_t)(L) * (size_t)N * 2u, N)
        LAUNCH_FINE(8);  LAUNCH_FINE(9);  LAUNCH_FINE(10); LAUNCH_FINE(11);
        LAUNCH_FINE(12); LAUNCH_FINE(13); LAUNCH_FINE(14); LAUNCH_FINE(15);
        #undef LAUNCH_FINE

        const int gridM = (N + 511) / 512;     // 512 pts/block MLP
        mlp_kernel<<<gridM, block, 0, stream>>>(enc, xs, W0, b0, W1, b1, W2, b2, out, N);
    } else if (ws_size >= encB) {
        float* enc = (float*)d_ws;
        encode_coarse_unsorted_kernel<<<grid, block, 0, stream>>>(x, table, enc, N, sc);
        for (int l = 5; l < NLV; ++l) {
            encode_one_unsorted_kernel<<<grid, block, 0, stream>>>(
                x, table + (size_t)l * T_SIZE * 2u, sc.s[l],
                enc + (size_t)l * (size_t)N * 2u, N);
        }
        mlp_noperm_kernel<<<grid, block, 0, stream>>>(enc, W0, b0, W1, b1, W2, b2, out, N);
    } else {
        tcnn_fused_kernel<<<grid, block, 0, stream>>>(x, table, W0, b0, W1, b1, W2, b2,
                                                      out, N, sc);
    }
}

// Round 11
// 504.016 us; speedup vs baseline: 1.0239x; 1.0239x over previous
//
#include <hip/hip_runtime.h>
#include <math.h>

#define NLV 16
#define LOG2_T 19
#define T_SIZE (1u << LOG2_T)
#define T_MASK (T_SIZE - 1u)
#define P2 2654435761u
#define P3 805459861u
#define NBUCK 32768   // 32^3 Morton buckets

typedef float vf2 __attribute__((ext_vector_type(2)));
typedef float vf4 __attribute__((ext_vector_type(4)));

struct Scales { float s[NLV]; };

// ---------- Morton key (5 bits/axis) ----------
__device__ __forceinline__ unsigned mpart(unsigned v) {
    v = (v | (v << 8)) & 0x100Fu;
    v = (v | (v << 4)) & 0x10C3u;
    v = (v | (v << 2)) & 0x1249u;
    return v;
}
__device__ __forceinline__ unsigned mkey(float px, float py, float pz) {
    unsigned cx = (unsigned)(px * 32.f); cx = cx > 31u ? 31u : cx;
    unsigned cy = (unsigned)(py * 32.f); cy = cy > 31u ? 31u : cy;
    unsigned cz = (unsigned)(pz * 32.f); cz = cz > 31u ? 31u : cz;
    return mpart(cx) | (mpart(cy) << 1) | (mpart(cz) << 2);
}

// ---------- sort kernels (1 pt/thread: latency-bound, maximize wave count) ----------
__global__ __launch_bounds__(256) void zero_hist_kernel(unsigned* hist) {
    int i = blockIdx.x * 256 + threadIdx.x;
    if (i < NBUCK) hist[i] = 0u;
}

__global__ __launch_bounds__(256) void hist_kernel(
    const float* __restrict__ x, unsigned* __restrict__ hist, int N)
{
    const int i = blockIdx.x * 256 + threadIdx.x;
    if (i >= N) return;
    const float px = x[3 * (size_t)i + 0];
    const float py = x[3 * (size_t)i + 1];
    const float pz = x[3 * (size_t)i + 2];
    atomicAdd(&hist[mkey(px, py, pz)], 1u);
}

__global__ __launch_bounds__(1024) void scan_kernel(unsigned* hist) {
    __shared__ unsigned tot[1024];
    const int t = threadIdx.x;
    const unsigned base = (unsigned)t * 32u;
    unsigned loc[32];
    unsigned s = 0;
    #pragma unroll
    for (int k = 0; k < 32; ++k) { loc[k] = s; s += hist[base + k]; }
    tot[t] = s;
    __syncthreads();
    for (int off = 1; off < 1024; off <<= 1) {
        unsigned u = (t >= off) ? tot[t - off] : 0u;
        __syncthreads();
        tot[t] += u;
        __syncthreads();
    }
    const unsigned excl = tot[t] - s;
    #pragma unroll
    for (int k = 0; k < 32; ++k) hist[base + k] = excl + loc[k];
}

// One 16B record per point: {px,py,pz, bitcast(idx)} -> single line touch.
__global__ __launch_bounds__(256) void scatter_kernel(
    const float* __restrict__ x, unsigned* __restrict__ cursor,
    vf4* __restrict__ xs, int N)
{
    const int i = blockIdx.x * 256 + threadIdx.x;
    if (i >= N) return;
    const float px = x[3 * (size_t)i + 0];
    const float py = x[3 * (size_t)i + 1];
    const float pz = x[3 * (size_t)i + 2];
    const unsigned key = mkey(px, py, pz);
    const unsigned pos = atomicAdd(&cursor[key], 1u);
    vf4 v; v[0] = px; v[1] = py; v[2] = pz; v[3] = __int_as_float(i);
    xs[pos] = v;
}

// ---------- encode ----------
// PRIMES[0]==1 => h is linear in ix: h(ix+1) = h(ix)^1 when ix is even.
// The two x-corners then sit in one 16B-aligned entry pair -> one vf4 load
// fetches both (8 -> 4 L2 requests/point). Odd ix keeps the 8-load path.
// Both paths load identical floats and accumulate in identical c-order ->
// bit-identical results.
__device__ __forceinline__ void enc_level(
    float px, float py, float pz, float s, const float* __restrict__ tl,
    float& f0, float& f1)
{
    const float fx = px * s, fy = py * s, fz = pz * s;
    const float bx = floorf(fx), by = floorf(fy), bz = floorf(fz);
    const float rx = fx - bx, ry = fy - by, rz = fz - bz;
    const unsigned ix0 = (unsigned)bx, iy0 = (unsigned)by, iz0 = (unsigned)bz;
    const unsigned hy0 = iy0 * P2, hy1 = (iy0 + 1u) * P2;
    const unsigned hz0 = iz0 * P3, hz1 = (iz0 + 1u) * P3;
    const float wx0 = 1.f - rx, wy0 = 1.f - ry, wz0 = 1.f - rz;
    f0 = 0.f; f1 = 0.f;
    if (!(ix0 & 1u)) {
        float c0[8], c1[8];
        #pragma unroll
        for (int yz = 0; yz < 4; ++yz) {
            const unsigned r = ((yz & 2) ? hy1 : hy0) ^ ((yz & 1) ? hz1 : hz0);
            const unsigned h0 = (ix0 ^ r) & T_MASK;
            const vf4 q = *(const vf4*)(tl + 2u * (size_t)(h0 & ~1u));
            const bool odd = (h0 & 1u) != 0u;
            c0[yz]     = odd ? q[2] : q[0];   // corner (0,y,z) feature 0
            c1[yz]     = odd ? q[3] : q[1];   // corner (0,y,z) feature 1
            c0[4 + yz] = odd ? q[0] : q[2];   // corner (1,y,z) feature 0
            c1[4 + yz] = odd ? q[1] : q[3];   // corner (1,y,z) feature 1
        }
        #pragma unroll
        for (int c = 0; c < 8; ++c) {
            const float w = ((c & 4) ? rx : wx0) * ((c & 2) ? ry : wy0) * ((c & 1) ? rz : wz0);
            f0 += w * c0[(c >> 2) * 4 + (c & 3)];
            f1 += w * c1[(c >> 2) * 4 + (c & 3)];
        }
    } else {
        const unsigned hx0 = ix0, hx1 = ix0 + 1u;
        #pragma unroll
        for (int c = 0; c < 8; ++c) {
            unsigned h = ((c & 4) ? hx1 : hx0) ^ ((c & 2) ? hy1 : hy0) ^ ((c & 1) ? hz1 : hz0);
            h &= T_MASK;
            const vf2 f = *(const vf2*)(tl + 2u * (size_t)h);
            const float w = ((c & 4) ? rx : wx0) * ((c & 2) ? ry : wy0) * ((c & 1) ? rz : wz0);
            f0 += w * f[0];
            f1 += w * f[1];
        }
    }
}

// Levels 0..4 fused (working sets co-resident in L2, L1-friendly after sort).
__global__ __launch_bounds__(256) void encode_coarse_kernel(
    const vf4* __restrict__ xs, const float* __restrict__ table,
    float* __restrict__ enc, int N, Scales sc)
{
    int i = blockIdx.x * 256 + threadIdx.x;
    if (i >= N) return;
    const vf4 p = xs[i];
    #pragma unroll
    for (int l = 0; l < 5; ++l) {
        float f0, f1;
        enc_level(p[0], p[1], p[2], sc.s[l], table + (size_t)l * T_SIZE * 2u, f0, f1);
        vf2 v; v[0] = f0; v[1] = f1;
        *(vf2*)(enc + ((size_t)l * N + i) * 2u) = v;
    }
}

// One fine level per launch; 4 points/thread; LVL tag -> per-level rocprof rows.
template<int LVL>
__global__ __launch_bounds__(256) void encode_fine_kernel(
    const vf4* __restrict__ xs, const float* __restrict__ tl, float s,
    float* __restrict__ encl, int N)
{
    const int i0 = blockIdx.x * 1024 + threadIdx.x;
    #pragma unroll
    for (int k = 0; k < 4; ++k) {
        const int i = i0 + k * 256;
        if (i < N) {
            const vf4 p = xs[i];
            float f0, f1;
            enc_level(p[0], p[1], p[2], s, tl, f0, f1);
            vf2 v; v[0] = f0; v[1] = f1;
            *(vf2*)(encl + (size_t)i * 2u) = v;
        }
    }
}

// ---------- MLP: 512 pts/block in two 256-pt halves (17 KB LDS -> 8 blocks/CU),
// float2-pair accumulation, LDS-staged cooperative NT store ----------
__global__ __launch_bounds__(256) void mlp_kernel(
    const float* __restrict__ enc, const vf4* __restrict__ xs,
    const float* __restrict__ W0, const float* __restrict__ b0,
    const float* __restrict__ W1, const float* __restrict__ b1,
    const float* __restrict__ W2, const float* __restrict__ b2,
    float* __restrict__ out, int N)
{
    __shared__ float st[256 * 17];   // 17408 B
    const int base = blockIdx.x * 512;
    const int t = threadIdx.x;
    const float* xsf = (const float*)xs;

    #pragma unroll
    for (int q = 0; q < 2; ++q) {
        if (q) __syncthreads();              // st reuse hazard (uniform branch)
        const int i = base + q * 256 + t;
        if (i < N) {
            vf2 e2[16];
            #pragma unroll
            for (int l = 0; l < NLV; ++l)
                e2[l] = *(const vf2*)(enc + ((size_t)l * N + i) * 2u);

            vf2 a0v[8];
            #pragma unroll
            for (int j = 0; j < 16; ++j) {
                vf2 acc = {0.f, 0.f};
                #pragma unroll
                for (int l = 0; l < 16; ++l)
                    acc += e2[l] * *(const vf2*)(W0 + j * 32 + 2 * l);
                a0v[j >> 1][j & 1] = fmaxf(b0[j] + acc[0] + acc[1], 0.f);
            }
            vf2 a1v[8];
            #pragma unroll
            for (int j = 0; j < 16; ++j) {
                vf2 acc = {0.f, 0.f};
                #pragma unroll
                for (int k = 0; k < 8; ++k)
                    acc += a0v[k] * *(const vf2*)(W1 + j * 16 + 2 * k);
                a1v[j >> 1][j & 1] = fmaxf(b1[j] + acc[0] + acc[1], 0.f);
            }
            #pragma unroll
            for (int j = 0; j < 16; ++j) {
                vf2 acc = {0.f, 0.f};
                #pragma unroll
                for (int k = 0; k < 8; ++k)
                    acc += a1v[k] * *(const vf2*)(W2 + j * 16 + 2 * k);
                st[t * 17 + j] = b2[j] + acc[0] + acc[1];
            }
        }
        __syncthreads();

        // 4 lanes per point; the 4 x 16B quarters of each output line coalesce
        // into one full-line NT write (no L2 allocation, out is never re-read).
        const int c = t & 3;
        #pragma unroll
        for (int w = 0; w < 4; ++w) {
            const int p = (t >> 2) + w * 64;          // local row 0..255
            const int gi = base + q * 256 + p;
            if (gi < N) {
                const int dst = __float_as_int(xsf[4 * (size_t)gi + 3]);
                const vf4 v = *(const vf4*)&st[p * 17 + 4 * c];
                __builtin_nontemporal_store(v, (vf4*)(out + 16 * (size_t)dst + 4 * c));
            }
        }
    }
}

// ---------- fallback paths ----------
__global__ __launch_bounds__(256) void encode_coarse_unsorted_kernel(
    const float* __restrict__ x, const float* __restrict__ table,
    float* __restrict__ enc, int N, Scales sc)
{
    int i = blockIdx.x * 256 + threadIdx.x;
    if (i >= N) return;
    const float px = x[3 * (size_t)i + 0];
    const float py = x[3 * (size_t)i + 1];
    const float pz = x[3 * (size_t)i + 2];
    #pragma unroll
    for (int l = 0; l < 5; ++l) {
        float f0, f1;
        enc_level(px, py, pz, sc.s[l], table + (size_t)l * T_SIZE * 2u, f0, f1);
        vf2 v; v[0] = f0; v[1] = f1;
        *(vf2*)(enc + ((size_t)l * N + i) * 2u) = v;
    }
}
__global__ __launch_bounds__(256) void encode_one_unsorted_kernel(
    const float* __restrict__ x, const float* __restrict__ tl, float s,
    float* __restrict__ encl, int N)
{
    int i = blockIdx.x * 256 + threadIdx.x;
    if (i >= N) return;
    const float px = x[3 * (size_t)i + 0];
    const float py = x[3 * (size_t)i + 1];
    const float pz = x[3 * (size_t)i + 2];
    float f0, f1;
    enc_level(px, py, pz, s, tl, f0, f1);
    vf2 v; v[0] = f0; v[1] = f1;
    *(vf2*)(encl + (size_t)i * 2u) = v;
}
__global__ __launch_bounds__(256) void mlp_noperm_kernel(
    const float* __restrict__ enc,
    const float* __restrict__ W0, const float* __restrict__ b0,
    const float* __restrict__ W1, const float* __restrict__ b1,
    const float* __restrict__ W2, const float* __restrict__ b2,
    float* __restrict__ out, int N)
{
    int i = blockIdx.x * 256 + threadIdx.x;
    if (i >= N) return;
    float e[32];
    #pragma unroll
    for (int l = 0; l < NLV; ++l) {
        vf2 v = *(const vf2*)(enc + ((size_t)l * N + i) * 2u);
        e[2 * l + 0] = v[0];
        e[2 * l + 1] = v[1];
    }
    float a0[16];
    #pragma unroll
    for (int j = 0; j < 16; ++j) {
        float s = b0[j];
        #pragma unroll
        for (int k = 0; k < 32; ++k) s += e[k] * W0[j * 32 + k];
        a0[j] = fmaxf(s, 0.f);
    }
    float a1[16];
    #pragma unroll
    for (int j = 0; j < 16; ++j) {
        float s = b1[j];
        #pragma unroll
        for (int k = 0; k < 16; ++k) s += a0[k] * W1[j * 16 + k];
        a1[j] = fmaxf(s, 0.f);
    }
    #pragma unroll
    for (int j = 0; j < 16; ++j) {
        float s = b2[j];
        #pragma unroll
        for (int k = 0; k < 16; ++k) s += a1[k] * W2[j * 16 + k];
        out[16 * (size_t)i + j] = s;
    }
}
__global__ __launch_bounds__(256) void tcnn_fused_kernel(
    const float* __restrict__ x, const float* __restrict__ table,
    const float* __restrict__ W0, const float* __restrict__ b0,
    const float* __restrict__ W1, const float* __restrict__ b1,
    const float* __restrict__ W2, const float* __restrict__ b2,
    float* __restrict__ out, int N, Scales sc)
{
    int i = blockIdx.x * blockDim.x + threadIdx.x;
    if (i >= N) return;
    const float px = x[3 * (size_t)i + 0];
    const float py = x[3 * (size_t)i + 1];
    const float pz = x[3 * (size_t)i + 2];
    float e[32];
    #pragma unroll
    for (int l = 0; l < NLV; ++l) {
        float f0, f1;
        enc_level(px, py, pz, sc.s[l], table + (size_t)l * T_SIZE * 2u, f0, f1);
        e[2 * l] = f0; e[2 * l + 1] = f1;
    }
    float a0[16];
    #pragma unroll
    for (int j = 0; j < 16; ++j) {
        float s = b0[j];
        #pragma unroll
        for (int k = 0; k < 32; ++k) s += e[k] * W0[j * 32 + k];
        a0[j] = fmaxf(s, 0.f);
    }
    float a1[16];
    #pragma unroll
    for (int j = 0; j < 16; ++j) {
        float s = b1[j];
        #pragma unroll
        for (int k = 0; k < 16; ++k) s += a0[k] * W1[j * 16 + k];
        a1[j] = fmaxf(s, 0.f);
    }
    #pragma unroll
    for (int j = 0; j < 16; ++j) {
        float s = b2[j];
        #pragma unroll
        for (int k = 0; k < 16; ++k) s += a1[k] * W2[j * 16 + k];
        out[16 * (size_t)i + j] = s;
    }
}

extern "C" void kernel_launch(void* const* d_in, const int* in_sizes, int n_in,
                              void* d_out, int out_size, void* d_ws, size_t ws_size,
                              hipStream_t stream) {
    const float* x     = (const float*)d_in[0];
    const float* table = (const float*)d_in[1];
    const float* W0    = (const float*)d_in[2];
    const float* b0    = (const float*)d_in[3];
    const float* W1    = (const float*)d_in[4];
    const float* b1    = (const float*)d_in[5];
    const float* W2    = (const float*)d_in[6];
    const float* b2    = (const float*)d_in[7];
    float* out = (float*)d_out;

    const int N = in_sizes[0] / 3;

    Scales sc;
    const double pls = exp2(log2(2048.0 / 16.0) / 15.0);  // matches numpy double math
    for (int l = 0; l < NLV; ++l) sc.s[l] = (float)(16.0 * pow(pls, (double)l));

    const int block = 256;
    const int grid = (N + block - 1) / block;

    const size_t encB  = (size_t)N * 2u * NLV * sizeof(float);   // 128 MiB
    const size_t xsB   = (size_t)N * sizeof(float) * 4u;         //  16 MiB
    const size_t histB = (size_t)NBUCK * sizeof(unsigned);

    if (ws_size >= encB + xsB + histB) {
        float*    enc  = (float*)d_ws;
        vf4*      xs   = (vf4*)((char*)d_ws + encB);
        unsigned* hist = (unsigned*)((char*)d_ws + encB + xsB);

        zero_hist_kernel<<<(NBUCK + 255) / 256, block, 0, stream>>>(hist);
        hist_kernel<<<grid, block, 0, stream>>>(x, hist, N);
        scan_kernel<<<1, 1024, 0, stream>>>(hist);
        scatter_kernel<<<grid, block, 0, stream>>>(x, hist, xs, N);

        encode_coarse_kernel<<<grid, block, 0, stream>>>(xs, table, enc, N, sc);

        const int gridQ = (N + 1023) / 1024;   // 4 pts/thread fine kernels
        #define LAUNCH_FINE(L) \
            encode_fine_kernel<L><<<gridQ, block, 0, stream>>>( \
                xs, table + (size_t)(L) * T_SIZE * 2u, sc.s[(L)], \
                enc + (size_t)(L) * (size_t)N * 2u, N)
        LAUNCH_FINE(5);  LAUNCH_FINE(6);  LAUNCH_FINE(7);  LAUNCH_FINE(8);
        LAUNCH_FINE(9);  LAUNCH_FINE(10); LAUNCH_FINE(11); LAUNCH_FINE(12);
        LAUNCH_FINE(13); LAUNCH_FINE(14); LAUNCH_FINE(15);
        #undef LAUNCH_FINE

        const int gridM = (N + 511) / 512;     // 512 pts/block MLP
        mlp_kernel<<<gridM, block, 0, stream>>>(enc, xs, W0, b0, W1, b1, W2, b2, out, N);
    } else if (ws_size >= encB) {
        float* enc = (float*)d_ws;
        encode_coarse_unsorted_kernel<<<grid, block, 0, stream>>>(x, table, enc, N, sc);
        for (int l = 5; l < NLV; ++l) {
            encode_one_unsorted_kernel<<<grid, block, 0, stream>>>(
                x, table + (size_t)l * T_SIZE * 2u, sc.s[l],
                enc + (size_t)l * (size_t)N * 2u, N);
        }
        mlp_noperm_kernel<<<grid, block, 0, stream>>>(enc, W0, b0, W1, b1, W2, b2, out, N);
    } else {
        tcnn_fused_kernel<<<grid, block, 0, stream>>>(x, table, W0, b0, W1, b1, W2, b2,
                                                      out, N, sc);
    }
}